// Round 6
// baseline (438.132 us; speedup 1.0000x reference)
//
#include <hip/hip_runtime.h>

#define NN 50000
#define NE 200000
#define DD 384

typedef unsigned short u16;
typedef unsigned int   u32;
typedef __attribute__((ext_vector_type(8))) __bf16 bf16x8;
typedef __attribute__((ext_vector_type(8))) short  short8;
typedef __attribute__((ext_vector_type(4))) float  f32x4;

// ---------- bf16 helpers (raw ushort storage) ----------
__device__ __forceinline__ float bf2f(u16 v) {
    union { u32 u; float f; } x; x.u = ((u32)v) << 16; return x.f;
}
__device__ __forceinline__ u16 f2bf(float f) {
    union { float f; u32 u; } x; x.f = f;
    u32 r = x.u + 0x7fff + ((x.u >> 16) & 1);   // RNE
    return (u16)(r >> 16);
}

// async global->LDS, 16B per lane. LDS dest = wave-uniform base + lane*16
// (HW rule, m104/m108); our staging layout is exactly that.
__device__ __forceinline__ void gload16(const void* g, void* l) {
    __builtin_amdgcn_global_load_lds(
        (const __attribute__((address_space(1))) u32*)g,
        (__attribute__((address_space(3))) u32*)l, 16, 0, 0);
}

__device__ __forceinline__ float ldf(const void* p, size_t i, int dt) {
    return dt ? ((const float*)p)[i] : bf2f(((const u16*)p)[i]);
}

// ---------- detect dtype (block 0) + zero cnt (blocks 1..196) ----------
__global__ __launch_bounds__(256) void detect0_k(const u16* __restrict__ p,
                                                 int* __restrict__ flag,
                                                 int* __restrict__ cnt) {
    const int b = blockIdx.x;
    if (b == 0) {
        __shared__ int tot;
        if (threadIdx.x == 0) tot = 0;
        __syncthreads();
        int bad = 0;
        for (int i = threadIdx.x; i < 8192; i += 256) {
            u16 v = p[i];
            int e = (v >> 7) & 0xFF;
            if (e >= 0x86) bad++;
        }
        atomicAdd(&tot, bad);
        __syncthreads();
        if (threadIdx.x == 0) flag[0] = (tot > 400) ? 1 : 0;
        return;
    }
    int i = (b - 1) * 256 + threadIdx.x;
    if (i < NN) cnt[i] = 0;
}

// ---------- fused prologue: hist | cast(emb->bf16) | packw ----------
// All independent given: cnt zeroed (detect0_k, previous kernel) and dtf
// written (detect0_k block 0). hist first so its atomics overlap cast.
// blocks [0,782): hist; [782,782+9375): cast; [10157,10157+2304): packw.
__global__ __launch_bounds__(256) void prolog_k(
    const void* __restrict__ emb, u16* __restrict__ ebf,
    const void* __restrict__ WQ, const void* __restrict__ WK,
    const void* __restrict__ WV, const void* __restrict__ WO,
    u16* __restrict__ Wt, int* __restrict__ cnt,
    const int* __restrict__ eidx, const int* __restrict__ dtf) {
    const int b = blockIdx.x;
    if (b < 782) {
        int e = b * 256 + threadIdx.x;
        if (e < NE) {
            int d = eidx[NE + e];
            if ((u32)d < NN) atomicAdd(&cnt[d], 1);
        }
        return;
    }
    if (b < 782 + 9375) {
        size_t i = ((size_t)(b - 782) * 256 + threadIdx.x) * 8;
        if (i >= (size_t)NN * 384) return;
        if (dtf[0]) {
            const float* s = (const float*)emb + i;
            f32x4 a0 = *(const f32x4*)s;
            f32x4 a1 = *(const f32x4*)(s + 4);
            short8 o;
            o[0] = (short)f2bf(a0[0]); o[1] = (short)f2bf(a0[1]);
            o[2] = (short)f2bf(a0[2]); o[3] = (short)f2bf(a0[3]);
            o[4] = (short)f2bf(a1[0]); o[5] = (short)f2bf(a1[1]);
            o[6] = (short)f2bf(a1[2]); o[7] = (short)f2bf(a1[3]);
            *(short8*)(ebf + i) = o;
        } else {
            *(short8*)(ebf + i) = *(const short8*)((const u16*)emb + i);
        }
        return;
    }
    int idx = (b - 782 - 9375) * 256 + threadIdx.x;
    if (idx >= 1536 * 384) return;
    int dt = dtf[0];
    int n = idx / 384, k = idx - n * 384;
    const void* W; int c;
    if (n < 384)       { W = WQ; c = n; }
    else if (n < 768)  { W = WK; c = n - 384; }
    else if (n < 1152) { W = WV; c = n - 768; }
    else               { W = WO; c = n - 1152; }
    size_t off = (size_t)k * 384 + c;
    Wt[idx] = dt ? f2bf(((const float*)W)[off]) : ((const u16*)W)[off];
}

// ---------- single-block full scan: indptr = exclusive scan of cnt ----------
// 1024 threads, 49 chunks of 1024. Wave-shuffle inclusive scan (no syncs),
// wave totals through double-buffered LDS (1 sync/chunk), prefetch-1-ahead.
// Also resets cnt to 0 (scatter's cursor).
__global__ __launch_bounds__(1024) void scanall_k(int* __restrict__ cnt,
                                                  int* __restrict__ indptr) {
    __shared__ int wtot[2][16];
    const int tid  = threadIdx.x;
    const int lane = tid & 63;
    const int w    = tid >> 6;          // 0..15
    if (tid == 0) indptr[0] = 0;
    int base = 0;
    int v = (tid < NN) ? cnt[tid] : 0;  // chunk 0 preload
    #pragma unroll 1
    for (int c = 0; c < 49; ++c) {
        int i = c * 1024 + tid;
        int nv = 0;
        if (c < 48) {
            int ni = i + 1024;
            nv = (ni < NN) ? cnt[ni] : 0;   // prefetch next chunk
        }
        // wave-local inclusive scan
        int s = v;
        #pragma unroll
        for (int off = 1; off < 64; off <<= 1) {
            int t = __shfl_up(s, off, 64);
            s += (lane >= off) ? t : 0;
        }
        if (lane == 63) wtot[c & 1][w] = s;
        __syncthreads();
        int wpre = 0, total = 0;
        #pragma unroll
        for (int k = 0; k < 16; ++k) {
            int t = wtot[c & 1][k];
            wpre  += (k < w) ? t : 0;
            total += t;
        }
        if (i < NN) { indptr[i + 1] = base + wpre + s; cnt[i] = 0; }
        base += total;
        v = nv;
        // next chunk writes wtot[(c+1)&1] (other buffer) -> no extra sync
    }
}

// ---------- MFMA GEMM, XCD-swizzled 1-D grid ----------
// 128x128 tile, 4 waves 2x2, 4x4 frags of 16x16x32 bf16. A always bf16.
// Staging via global_load_lds width=16 (m93->m97 rung).
// MODE 0 (QKV): n<384 -> q (ld 384), n>=384 -> kv (ld 768).
//   blocks >= 392*NT are SCATTER riders (CSR edge-id scatter) — independent
//   work gated on the same predecessors; attn (next kernel) needs both.
// MODE 1 (OUT): C = bf16 preln = acc + resid (fp32/bf16 per flag).
// NOTE: preln must NOT alias A — sibling n-tile blocks of the same m-tile
// read ALL 384 columns of the A rows this block writes (R6 race).
template <int MODE, int NT>
__global__ __launch_bounds__(256) void gemm_k(
    const u16* __restrict__ A, const u16* __restrict__ Bt,
    u16* __restrict__ qd, u16* __restrict__ kvd, u16* __restrict__ preln,
    const void* __restrict__ resid, const int* __restrict__ dtf, int M,
    const int* __restrict__ eidx, const int* __restrict__ indptr,
    int* __restrict__ cur, int* __restrict__ eids) {
    __shared__ __align__(16) short As[128 * 32];
    __shared__ __align__(16) short Bs[128 * 32];
    const int b    = blockIdx.x;
    if (MODE == 0 && b >= 392 * NT) {
        int e = (b - 392 * NT) * 256 + threadIdx.x;
        if (e < NE) {
            int d = eidx[NE + e];
            if ((u32)d < NN) {
                int p = atomicAdd(&cur[d], 1);
                int slot = indptr[d] + p;
                if ((u32)slot < NE) eids[slot] = e;
            }
        }
        return;
    }
    const int xcd  = b & 7;
    const int j    = b >> 3;
    const int mg   = j / NT;
    const int nt   = j - mg * NT;
    const int m_idx = mg * 8 + xcd;
    if (m_idx >= (M + 127) / 128) return;
    const int m0 = m_idx * 128;
    const int n0 = nt * 128;
    const int tid  = threadIdx.x;
    const int lane = tid & 63;
    const int wave = tid >> 6;
    const int wm = (wave >> 1) * 64;
    const int wn = (wave & 1) * 64;
    const int q = lane >> 4;     // 0..3
    const int r = lane & 15;     // 0..15
    const int dt = (MODE == 1) ? dtf[0] : 0;

    f32x4 acc[4][4];
    #pragma unroll
    for (int i = 0; i < 4; i++)
        #pragma unroll
        for (int jj = 0; jj < 4; jj++) acc[i][jj] = (f32x4)(0.0f);

    const int srow = tid >> 2;          // 0..63
    const int scol = (tid & 3) * 8;     // element offset in 32-wide K block

    for (int kb = 0; kb < 12; ++kb) {
        const int k0 = kb * 32;
        #pragma unroll
        for (int h = 0; h < 2; ++h) {
            int row = h * 64 + srow;
            int am = m0 + row; am = am < M ? am : M - 1;
            // LDS dest: shorts h*2048 + wave*512 (+ lane*8 shorts by HW)
            gload16(A  + (size_t)am * 384 + k0 + scol,
                    (void*)(As + h * 2048 + wave * 512));
            gload16(Bt + (size_t)(n0 + row) * 384 + k0 + scol,
                    (void*)(Bs + h * 2048 + wave * 512));
        }
        __syncthreads();            // compiler emits vmcnt(0) drain here
        bf16x8 af[4], bfr[4];
        #pragma unroll
        for (int i = 0; i < 4; i++)
            af[i] = *(const bf16x8*)&As[(wm + i * 16 + r) * 32 + q * 8];
        #pragma unroll
        for (int jj = 0; jj < 4; jj++)
            bfr[jj] = *(const bf16x8*)&Bs[(wn + jj * 16 + r) * 32 + q * 8];
        #pragma unroll
        for (int i = 0; i < 4; i++)
            #pragma unroll
            for (int jj = 0; jj < 4; jj++)
                acc[i][jj] = __builtin_amdgcn_mfma_f32_16x16x32_bf16(
                    af[i], bfr[jj], acc[i][jj], 0, 0, 0);
        __syncthreads();
    }

    // block-uniform destination routing
    u16* C; int ld, c0;
    if (MODE == 0) {
        if (n0 < 384) { C = qd;  ld = 384; c0 = n0; }
        else          { C = kvd; ld = 768; c0 = n0 - 384; }
    } else {
        C = preln; ld = 384; c0 = n0;
    }

    // D layout: col = lane&15, row = (lane>>4)*4 + reg   [measured m89/m91]
    #pragma unroll
    for (int i = 0; i < 4; i++) {
        #pragma unroll
        for (int rr = 0; rr < 4; ++rr) {
            int m = m0 + wm + i * 16 + q * 4 + rr;
            if (m >= M) continue;
            #pragma unroll
            for (int jj = 0; jj < 4; jj++) {
                int n = c0 + wn + jj * 16 + r;
                float v = acc[i][jj][rr];
                if (MODE == 1)
                    v += ldf(resid, (size_t)m * 384 + n, dt);
                C[(size_t)m * ld + n] = f2bf(v);
            }
        }
    }
}

// ---------- per-node attention ----------
// wave per node; lanes 0-31 = head0, 32-63 = head1; 6 elems/lane (192/32).
__global__ __launch_bounds__(256) void attn_k(
    u16* __restrict__ qbuf,              // [NN][384] bf16, becomes agg
    const u16* __restrict__ kv,          // [NN][768] bf16 = k|v
    const int* __restrict__ eidx,
    const void* __restrict__ eattr, const void* __restrict__ WE,
    const int* __restrict__ indptr, const int* __restrict__ eids,
    const int* __restrict__ dtf) {
    int node = blockIdx.x * 4 + (threadIdx.x >> 6);
    if (node >= NN) return;
    int dt = dtf[0];
    int lane = threadIdx.x & 63;
    int half = lane >> 5;
    int j = lane & 31;
    int col = half * 192 + j * 6;

    float qv[6], we[6];
    {
        const u32* p = (const u32*)(qbuf + (size_t)node * 384 + col);
        #pragma unroll
        for (int t = 0; t < 3; t++) {
            u32 w = p[t];
            qv[2 * t] = bf2f(w & 0xffff); qv[2 * t + 1] = bf2f(w >> 16);
        }
        #pragma unroll
        for (int t = 0; t < 6; t++) we[t] = ldf(WE, col + t, dt);
    }
    int beg = indptr[node], end = indptr[node + 1];
    if (beg < 0) beg = 0; if (beg > NE) beg = NE;
    if (end < beg) end = beg; if (end > NE) end = NE;
    float m_run = -1e30f, l_run = 0.0f;
    float acc[6] = {0, 0, 0, 0, 0, 0};

    for (int it = beg; it < end; ++it) {
        int eid = eids[it];
        if ((u32)eid >= NE) eid = 0;
        int src = eidx[eid];                    // row 0 = src
        if ((u32)src >= NN) src = 0;
        float attr = ldf(eattr, eid, dt);
        const u32* kp = (const u32*)(kv + (size_t)src * 768 + col);
        const u32* vp = (const u32*)(kv + (size_t)src * 768 + 384 + col);
        float kj[6], vj[6];
        #pragma unroll
        for (int t = 0; t < 3; t++) {
            u32 wk = kp[t];
            kj[2 * t]     = bf2f(wk & 0xffff) + attr * we[2 * t];
            kj[2 * t + 1] = bf2f(wk >> 16)    + attr * we[2 * t + 1];
            u32 wv = vp[t];
            vj[2 * t]     = bf2f(wv & 0xffff) + attr * we[2 * t];
            vj[2 * t + 1] = bf2f(wv >> 16)    + attr * we[2 * t + 1];
        }
        float part = qv[0] * kj[0] + qv[1] * kj[1] + qv[2] * kj[2] +
                     qv[3] * kj[3] + qv[4] * kj[4] + qv[5] * kj[5];
        #pragma unroll
        for (int off = 1; off < 32; off <<= 1) part += __shfl_xor(part, off, 64);
        float s = part * 0.07216878364870323f;   // 1/sqrt(192)
        float mn = fmaxf(m_run, s);
        float corr = __expf(m_run - mn);
        float p = __expf(s - mn);
        l_run = l_run * corr + p;
        #pragma unroll
        for (int t = 0; t < 6; t++) acc[t] = acc[t] * corr + p * vj[t];
        m_run = mn;
    }
    float inv = (end > beg) ? 1.0f / (l_run + 1e-16f) : 0.0f;
    u16* ar = qbuf + (size_t)node * 384 + col;   // in-place over q row
    #pragma unroll
    for (int t = 0; t < 6; t++) ar[t] = f2bf(acc[t] * inv);
}

// ---------- LayerNorm: wave per row; bf16 preln in, output dtype per flag ----
__global__ __launch_bounds__(256) void ln_k(const u16* __restrict__ x,
                                            const void* __restrict__ g,
                                            const void* __restrict__ b,
                                            void* __restrict__ out,
                                            const int* __restrict__ dtf) {
    int node = blockIdx.x * 4 + (threadIdx.x >> 6);
    if (node >= NN) return;
    int dt = dtf[0];
    int lane = threadIdx.x & 63;
    const u32* row = (const u32*)(x + (size_t)node * 384 + lane * 6);
    float v[6];
    #pragma unroll
    for (int t = 0; t < 3; t++) {
        u32 w = row[t];
        v[2 * t] = bf2f(w & 0xffff); v[2 * t + 1] = bf2f(w >> 16);
    }
    float s = v[0] + v[1] + v[2] + v[3] + v[4] + v[5];
    #pragma unroll
    for (int off = 1; off < 64; off <<= 1) s += __shfl_xor(s, off, 64);
    float mean = s * (1.0f / 384.0f);
    float sq = 0.0f;
    #pragma unroll
    for (int t = 0; t < 6; t++) { float d = v[t] - mean; sq += d * d; }
    #pragma unroll
    for (int off = 1; off < 64; off <<= 1) sq += __shfl_xor(sq, off, 64);
    float rstd = rsqrtf(sq * (1.0f / 384.0f) + 1e-5f);
    size_t o0 = (size_t)node * 384 + lane * 6;
    #pragma unroll
    for (int t = 0; t < 6; t++) {
        float gv = ldf(g, lane * 6 + t, dt), bv = ldf(b, lane * 6 + t, dt);
        float val = (v[t] - mean) * rstd * gv + bv;
        if (dt) ((float*)out)[o0 + t] = val;
        else    ((u16*)out)[o0 + t] = f2bf(val);
    }
}

// ---------- launch ----------
extern "C" void kernel_launch(void* const* d_in, const int* in_sizes, int n_in,
                              void* d_out, int out_size, void* d_ws, size_t ws_size,
                              hipStream_t stream) {
    const void* emb   = d_in[0];
    const int*  eidx  = (const int*)d_in[1];
    const void* eattr = d_in[2];
    const void* WQ    = d_in[3];
    const void* WK    = d_in[4];
    const void* WV    = d_in[5];
    const void* WE    = d_in[6];
    const void* WO    = d_in[7];
    const void* lng   = d_in[8];
    const void* lnb   = d_in[9];

    char* ws = (char*)d_ws;
    // ws layout — exactly 79,180,800 B:
    //   ints+flag+eids+Wt (2.38 MB) | ebf 38.4 MB | q/agg 38.4 MB
    // kv bf16 [NN][768] = 76.8 MB lives in d_out (dead until ln_k writes).
    // preln reuses the EBF region (dead after QKV GEMM) — never aliases A.
    const size_t OFF_IPTR = 0;           // (NN+1)*4 -> pad 200,064
    const size_t OFF_CNT  = 200064;      // NN*4 -> 400,064
    const size_t OFF_BSUM = 400064;      // 256*4 -> 401,088 (unused now)
    const size_t OFF_FLAG = 401088;      // 64 -> 401,152
    const size_t OFF_EIDS = 401152;      // NE*4 -> 1,201,152
    const size_t OFF_WT   = 1201152;     // 1536*384*2 -> 2,380,800
    const size_t OFF_EBF  = 2380800;     // 50000*384*2 -> 40,780,800
    const size_t OFF_Q    = 40780800;    // 50000*384*2 -> 79,180,800

    if (ws_size < 79180800) return;      // diagnostic guard

    int*   indptr = (int*)(ws + OFF_IPTR);
    int*   cnt    = (int*)(ws + OFF_CNT);
    int*   dtf    = (int*)(ws + OFF_FLAG);
    int*   eids   = (int*)(ws + OFF_EIDS);
    u16*   Wt     = (u16*)(ws + OFF_WT);
    u16*   ebf    = (u16*)(ws + OFF_EBF);     // bf16 embeddings, then preln
    u16*   qa     = (u16*)(ws + OFF_Q);       // q -> agg (in-place)
    u16*   preln  = ebf;                      // ebf dead after QKV GEMM
    u16*   kv     = (u16*)d_out;              // k|v, dead before final write

    // 7-node chain (was 11): detect0 -> prolog -> scanall -> gemmQKV+scatter
    //                        -> attn -> gemmOUT -> ln
    detect0_k<<<197, 256, 0, stream>>>((const u16*)emb, dtf, cnt);
    // hist | cast | packw : 782 + 9375 + 2304 = 12461 blocks
    prolog_k<<<12461, 256, 0, stream>>>(emb, ebf, WQ, WK, WV, WO, Wt, cnt,
                                        eidx, dtf);
    scanall_k<<<1, 1024, 0, stream>>>(cnt, indptr);

    // fused q|k|v projection (392 m-slots x 9 n-tiles) + 782 scatter riders
    gemm_k<0, 9><<<392 * 9 + 782, 256, 0, stream>>>(
        ebf, Wt, qa, kv, nullptr, nullptr, dtf, NN,
        eidx, indptr, cnt, eids);

    attn_k<<<(NN + 3) / 4, 256, 0, stream>>>(qa, kv, eidx, eattr, WE,
                                             indptr, eids, dtf);

    // output projection + residual -> preln (ebf region, disjoint from qa)
    gemm_k<1, 3><<<392 * 3, 256, 0, stream>>>(qa, Wt + 1152 * 384, nullptr,
                                              nullptr, preln, emb, dtf, NN,
                                              nullptr, nullptr, nullptr, nullptr);

    ln_k<<<(NN + 3) / 4, 256, 0, stream>>>(preln, lng, lnb, d_out, dtf);
}

// Round 8
// 405.290 us; speedup vs baseline: 1.0810x; 1.0810x over previous
//
#include <hip/hip_runtime.h>

#define NN 50000
#define NE 200000
#define DD 384

typedef unsigned short u16;
typedef unsigned int   u32;
typedef __attribute__((ext_vector_type(8))) __bf16 bf16x8;
typedef __attribute__((ext_vector_type(8))) short  short8;
typedef __attribute__((ext_vector_type(4))) float  f32x4;

// ---------- bf16 helpers (raw ushort storage) ----------
__device__ __forceinline__ float bf2f(u16 v) {
    union { u32 u; float f; } x; x.u = ((u32)v) << 16; return x.f;
}
__device__ __forceinline__ u16 f2bf(float f) {
    union { float f; u32 u; } x; x.f = f;
    u32 r = x.u + 0x7fff + ((x.u >> 16) & 1);   // RNE
    return (u16)(r >> 16);
}

// async global->LDS, 16B per lane. LDS dest = wave-uniform base + lane*16
// (HW rule, m104/m108); our staging layout is exactly that.
__device__ __forceinline__ void gload16(const void* g, void* l) {
    __builtin_amdgcn_global_load_lds(
        (const __attribute__((address_space(1))) u32*)g,
        (__attribute__((address_space(3))) u32*)l, 16, 0, 0);
}

// ---------- input dtype detector: flag=1 -> inputs are fp32 ----------
__global__ __launch_bounds__(256) void detect_k(const u16* __restrict__ p,
                                                int* __restrict__ flag) {
    __shared__ int tot;
    if (threadIdx.x == 0) tot = 0;
    __syncthreads();
    int bad = 0;
    for (int i = threadIdx.x; i < 8192; i += 256) {
        u16 v = p[i];
        int e = (v >> 7) & 0xFF;
        if (e >= 0x86) bad++;
    }
    atomicAdd(&tot, bad);
    __syncthreads();
    if (threadIdx.x == 0) flag[0] = (tot > 400) ? 1 : 0;
}

__device__ __forceinline__ float ldf(const void* p, size_t i, int dt) {
    return dt ? ((const float*)p)[i] : bf2f(((const u16*)p)[i]);
}

// ---------- fused prologue: zero(cnt) | cast(emb->bf16) | packw ----------
// blocks [0,196): zero cnt; [196,196+9375): cast; [9571,9571+2304): packw.
__global__ __launch_bounds__(256) void prolog_k(
    const void* __restrict__ emb, u16* __restrict__ ebf,
    const void* __restrict__ WQ, const void* __restrict__ WK,
    const void* __restrict__ WV, const void* __restrict__ WO,
    u16* __restrict__ Wt, int* __restrict__ cnt,
    const int* __restrict__ dtf) {
    const int b = blockIdx.x;
    if (b < 196) {
        int i = b * 256 + threadIdx.x;
        if (i < NN) cnt[i] = 0;
        return;
    }
    if (b < 196 + 9375) {
        size_t i = ((size_t)(b - 196) * 256 + threadIdx.x) * 8;
        if (i >= (size_t)NN * 384) return;
        if (dtf[0]) {
            const float* s = (const float*)emb + i;
            f32x4 a0 = *(const f32x4*)s;
            f32x4 a1 = *(const f32x4*)(s + 4);
            short8 o;
            o[0] = (short)f2bf(a0[0]); o[1] = (short)f2bf(a0[1]);
            o[2] = (short)f2bf(a0[2]); o[3] = (short)f2bf(a0[3]);
            o[4] = (short)f2bf(a1[0]); o[5] = (short)f2bf(a1[1]);
            o[6] = (short)f2bf(a1[2]); o[7] = (short)f2bf(a1[3]);
            *(short8*)(ebf + i) = o;
        } else {
            *(short8*)(ebf + i) = *(const short8*)((const u16*)emb + i);
        }
        return;
    }
    int idx = (b - 196 - 9375) * 256 + threadIdx.x;
    if (idx >= 1536 * 384) return;
    int dt = dtf[0];
    int n = idx / 384, k = idx - n * 384;
    const void* W; int c;
    if (n < 384)       { W = WQ; c = n; }
    else if (n < 768)  { W = WK; c = n - 384; }
    else if (n < 1152) { W = WV; c = n - 768; }
    else               { W = WO; c = n - 1152; }
    size_t off = (size_t)k * 384 + c;
    Wt[idx] = dt ? f2bf(((const float*)W)[off]) : ((const u16*)W)[off];
}

// ---------- CSR build ----------
__global__ void hist_k(const int* __restrict__ eidx, int* __restrict__ cnt) {
    int e = blockIdx.x * 256 + threadIdx.x;
    if (e < NE) {
        int d = eidx[NE + e];
        if ((u32)d < NN) atomicAdd(&cnt[d], 1);
    }
}
__global__ __launch_bounds__(256) void scan1_k(const int* __restrict__ cnt,
                                               int* __restrict__ indptr,
                                               int* __restrict__ bsum) {
    __shared__ int tmp[256];
    int i = blockIdx.x * 256 + threadIdx.x;
    int v = (i < NN) ? cnt[i] : 0;
    tmp[threadIdx.x] = v;
    __syncthreads();
    #pragma unroll
    for (int off = 1; off < 256; off <<= 1) {
        int t = tmp[threadIdx.x];
        int a = (threadIdx.x >= off) ? tmp[threadIdx.x - off] : 0;
        __syncthreads();
        tmp[threadIdx.x] = t + a;
        __syncthreads();
    }
    if (i < NN) indptr[i + 1] = tmp[threadIdx.x];
    if (threadIdx.x == 255) bsum[blockIdx.x] = tmp[255];
}
__global__ __launch_bounds__(256) void scan2_k(int* __restrict__ bsum, int nb) {
    __shared__ int tmp[256];
    int v = (threadIdx.x < nb) ? bsum[threadIdx.x] : 0;
    tmp[threadIdx.x] = v;
    __syncthreads();
    #pragma unroll
    for (int off = 1; off < 256; off <<= 1) {
        int t = tmp[threadIdx.x];
        int a = (threadIdx.x >= off) ? tmp[threadIdx.x - off] : 0;
        __syncthreads();
        tmp[threadIdx.x] = t + a;
        __syncthreads();
    }
    if (threadIdx.x < nb) bsum[threadIdx.x] = tmp[threadIdx.x] - v;  // exclusive
}
__global__ void scan3_k(int* __restrict__ indptr, const int* __restrict__ bsum,
                        int* __restrict__ cnt) {
    int i = blockIdx.x * 256 + threadIdx.x;
    if (i < NN) { indptr[i + 1] += bsum[blockIdx.x]; cnt[i] = 0; }
    if (i == 0) indptr[0] = 0;
}
__global__ void scatter_k(const int* __restrict__ eidx, const int* __restrict__ indptr,
                          int* __restrict__ cur, int* __restrict__ eids) {
    int e = blockIdx.x * 256 + threadIdx.x;
    if (e < NE) {
        int d = eidx[NE + e];
        if ((u32)d < NN) {
            int p = atomicAdd(&cur[d], 1);
            int slot = indptr[d] + p;
            if ((u32)slot < NE) eids[slot] = e;
        }
    }
}

// ---------- MFMA GEMM, XCD-swizzled 1-D grid, BK=64 ----------
// 128x128 tile, 4 waves 2x2, 4x4 frags of 16x16x32 bf16. A always bf16.
// BK=64: halves barrier-drain pairs (24 -> 12) vs BK=32; LDS = 2 K-slabs
// of [128][32] per matrix (32 KB total, ~5 blocks/CU). Slab stride 8192 B
// is bank-aligned -> ds_read bank pattern identical to BK=32 (conflict
// count is the control). Staging via global_load_lds width=16.
// MODE 0 (QKV): n<384 -> q (ld 384), n>=384 -> kv (ld 768).
// MODE 1 (OUT): C = bf16 preln = acc + resid (fp32/bf16 per flag).
// NOTE: preln must NOT alias A — sibling n-tile blocks of the same m-tile
// read ALL 384 columns of the A rows this block writes (R6 race).
template <int MODE, int NT>
__global__ __launch_bounds__(256) void gemm_k(
    const u16* __restrict__ A, const u16* __restrict__ Bt,
    u16* __restrict__ qd, u16* __restrict__ kvd, u16* __restrict__ preln,
    const void* __restrict__ resid, const int* __restrict__ dtf, int M) {
    __shared__ __align__(16) short As[2 * 128 * 32];   // slab ks: cols k0+ks*32..
    __shared__ __align__(16) short Bs[2 * 128 * 32];
    const int b    = blockIdx.x;
    const int xcd  = b & 7;
    const int j    = b >> 3;
    const int mg   = j / NT;
    const int nt   = j - mg * NT;
    const int m_idx = mg * 8 + xcd;
    if (m_idx >= (M + 127) / 128) return;
    const int m0 = m_idx * 128;
    const int n0 = nt * 128;
    const int tid  = threadIdx.x;
    const int lane = tid & 63;
    const int wave = tid >> 6;
    const int wm = (wave >> 1) * 64;
    const int wn = (wave & 1) * 64;
    const int q = lane >> 4;     // 0..3
    const int r = lane & 15;     // 0..15
    const int dt = (MODE == 1) ? dtf[0] : 0;

    f32x4 acc[4][4];
    #pragma unroll
    for (int i = 0; i < 4; i++)
        #pragma unroll
        for (int jj = 0; jj < 4; jj++) acc[i][jj] = (f32x4)(0.0f);

    const int srow = tid >> 2;          // 0..63
    const int scol = (tid & 3) * 8;     // element offset in 32-wide K slab

    for (int kb = 0; kb < 6; ++kb) {
        const int k0 = kb * 64;
        #pragma unroll
        for (int h = 0; h < 4; ++h) {
            const int slab = h >> 1;
            const int row  = (h & 1) * 64 + srow;          // 0..127
            const int col  = k0 + slab * 32 + scol;
            int am = m0 + row; am = am < M ? am : M - 1;
            // dest byte = h*4096 + tid*16 -> slab (h>>1), row, col8 (tid&3)
            gload16(A  + (size_t)am * 384 + col,
                    (void*)(As + h * 2048 + wave * 512));
            gload16(Bt + (size_t)(n0 + row) * 384 + col,
                    (void*)(Bs + h * 2048 + wave * 512));
        }
        __syncthreads();            // compiler emits vmcnt(0) drain here
        #pragma unroll
        for (int ks = 0; ks < 2; ++ks) {
            bf16x8 af[4], bfr[4];
            #pragma unroll
            for (int i = 0; i < 4; i++)
                af[i] = *(const bf16x8*)&As[ks * 4096 + (wm + i * 16 + r) * 32 + q * 8];
            #pragma unroll
            for (int jj = 0; jj < 4; jj++)
                bfr[jj] = *(const bf16x8*)&Bs[ks * 4096 + (wn + jj * 16 + r) * 32 + q * 8];
            #pragma unroll
            for (int i = 0; i < 4; i++)
                #pragma unroll
                for (int jj = 0; jj < 4; jj++)
                    acc[i][jj] = __builtin_amdgcn_mfma_f32_16x16x32_bf16(
                        af[i], bfr[jj], acc[i][jj], 0, 0, 0);
        }
        __syncthreads();
    }

    // block-uniform destination routing
    u16* C; int ld, c0;
    if (MODE == 0) {
        if (n0 < 384) { C = qd;  ld = 384; c0 = n0; }
        else          { C = kvd; ld = 768; c0 = n0 - 384; }
    } else {
        C = preln; ld = 384; c0 = n0;
    }

    // D layout: col = lane&15, row = (lane>>4)*4 + reg   [measured m89/m91]
    #pragma unroll
    for (int i = 0; i < 4; i++) {
        #pragma unroll
        for (int rr = 0; rr < 4; ++rr) {
            int m = m0 + wm + i * 16 + q * 4 + rr;
            if (m >= M) continue;
            #pragma unroll
            for (int jj = 0; jj < 4; jj++) {
                int n = c0 + wn + jj * 16 + r;
                float v = acc[i][jj][rr];
                if (MODE == 1)
                    v += ldf(resid, (size_t)m * 384 + n, dt);
                C[(size_t)m * ld + n] = f2bf(v);
            }
        }
    }
}

// ---------- per-node attention ----------
// wave per node; lanes 0-31 = head0, 32-63 = head1; 6 elems/lane (192/32).
__global__ __launch_bounds__(256) void attn_k(
    u16* __restrict__ qbuf,              // [NN][384] bf16, becomes agg
    const u16* __restrict__ kv,          // [NN][768] bf16 = k|v
    const int* __restrict__ eidx,
    const void* __restrict__ eattr, const void* __restrict__ WE,
    const int* __restrict__ indptr, const int* __restrict__ eids,
    const int* __restrict__ dtf) {
    int node = blockIdx.x * 4 + (threadIdx.x >> 6);
    if (node >= NN) return;
    int dt = dtf[0];
    int lane = threadIdx.x & 63;
    int half = lane >> 5;
    int j = lane & 31;
    int col = half * 192 + j * 6;

    float qv[6], we[6];
    {
        const u32* p = (const u32*)(qbuf + (size_t)node * 384 + col);
        #pragma unroll
        for (int t = 0; t < 3; t++) {
            u32 w = p[t];
            qv[2 * t] = bf2f(w & 0xffff); qv[2 * t + 1] = bf2f(w >> 16);
        }
        #pragma unroll
        for (int t = 0; t < 6; t++) we[t] = ldf(WE, col + t, dt);
    }
    int beg = indptr[node], end = indptr[node + 1];
    if (beg < 0) beg = 0; if (beg > NE) beg = NE;
    if (end < beg) end = beg; if (end > NE) end = NE;
    float m_run = -1e30f, l_run = 0.0f;
    float acc[6] = {0, 0, 0, 0, 0, 0};

    for (int it = beg; it < end; ++it) {
        int eid = eids[it];
        if ((u32)eid >= NE) eid = 0;
        int src = eidx[eid];                    // row 0 = src
        if ((u32)src >= NN) src = 0;
        float attr = ldf(eattr, eid, dt);
        const u32* kp = (const u32*)(kv + (size_t)src * 768 + col);
        const u32* vp = (const u32*)(kv + (size_t)src * 768 + 384 + col);
        float kj[6], vj[6];
        #pragma unroll
        for (int t = 0; t < 3; t++) {
            u32 wk = kp[t];
            kj[2 * t]     = bf2f(wk & 0xffff) + attr * we[2 * t];
            kj[2 * t + 1] = bf2f(wk >> 16)    + attr * we[2 * t + 1];
            u32 wv = vp[t];
            vj[2 * t]     = bf2f(wv & 0xffff) + attr * we[2 * t];
            vj[2 * t + 1] = bf2f(wv >> 16)    + attr * we[2 * t + 1];
        }
        float part = qv[0] * kj[0] + qv[1] * kj[1] + qv[2] * kj[2] +
                     qv[3] * kj[3] + qv[4] * kj[4] + qv[5] * kj[5];
        #pragma unroll
        for (int off = 1; off < 32; off <<= 1) part += __shfl_xor(part, off, 64);
        float s = part * 0.07216878364870323f;   // 1/sqrt(192)
        float mn = fmaxf(m_run, s);
        float corr = __expf(m_run - mn);
        float p = __expf(s - mn);
        l_run = l_run * corr + p;
        #pragma unroll
        for (int t = 0; t < 6; t++) acc[t] = acc[t] * corr + p * vj[t];
        m_run = mn;
    }
    float inv = (end > beg) ? 1.0f / (l_run + 1e-16f) : 0.0f;
    u16* ar = qbuf + (size_t)node * 384 + col;   // in-place over q row
    #pragma unroll
    for (int t = 0; t < 6; t++) ar[t] = f2bf(acc[t] * inv);
}

// ---------- LayerNorm: wave per row; bf16 preln in, output dtype per flag ----
__global__ __launch_bounds__(256) void ln_k(const u16* __restrict__ x,
                                            const void* __restrict__ g,
                                            const void* __restrict__ b,
                                            void* __restrict__ out,
                                            const int* __restrict__ dtf) {
    int node = blockIdx.x * 4 + (threadIdx.x >> 6);
    if (node >= NN) return;
    int dt = dtf[0];
    int lane = threadIdx.x & 63;
    const u32* row = (const u32*)(x + (size_t)node * 384 + lane * 6);
    float v[6];
    #pragma unroll
    for (int t = 0; t < 3; t++) {
        u32 w = row[t];
        v[2 * t] = bf2f(w & 0xffff); v[2 * t + 1] = bf2f(w >> 16);
    }
    float s = v[0] + v[1] + v[2] + v[3] + v[4] + v[5];
    #pragma unroll
    for (int off = 1; off < 64; off <<= 1) s += __shfl_xor(s, off, 64);
    float mean = s * (1.0f / 384.0f);
    float sq = 0.0f;
    #pragma unroll
    for (int t = 0; t < 6; t++) { float d = v[t] - mean; sq += d * d; }
    #pragma unroll
    for (int off = 1; off < 64; off <<= 1) sq += __shfl_xor(sq, off, 64);
    float rstd = rsqrtf(sq * (1.0f / 384.0f) + 1e-5f);
    size_t o0 = (size_t)node * 384 + lane * 6;
    #pragma unroll
    for (int t = 0; t < 6; t++) {
        float gv = ldf(g, lane * 6 + t, dt), bv = ldf(b, lane * 6 + t, dt);
        float val = (v[t] - mean) * rstd * gv + bv;
        if (dt) ((float*)out)[o0 + t] = val;
        else    ((u16*)out)[o0 + t] = f2bf(val);
    }
}

// ---------- launch ----------
extern "C" void kernel_launch(void* const* d_in, const int* in_sizes, int n_in,
                              void* d_out, int out_size, void* d_ws, size_t ws_size,
                              hipStream_t stream) {
    const void* emb   = d_in[0];
    const int*  eidx  = (const int*)d_in[1];
    const void* eattr = d_in[2];
    const void* WQ    = d_in[3];
    const void* WK    = d_in[4];
    const void* WV    = d_in[5];
    const void* WE    = d_in[6];
    const void* WO    = d_in[7];
    const void* lng   = d_in[8];
    const void* lnb   = d_in[9];

    char* ws = (char*)d_ws;
    // ws layout — exactly 79,180,800 B:
    //   ints+flag+eids+Wt (2.38 MB) | ebf 38.4 MB | q/agg 38.4 MB
    // kv bf16 [NN][768] = 76.8 MB lives in d_out (dead until ln_k writes).
    // preln reuses the EBF region (dead after QKV GEMM) — never aliases A.
    const size_t OFF_IPTR = 0;           // (NN+1)*4 -> pad 200,064
    const size_t OFF_CNT  = 200064;      // NN*4 -> 400,064
    const size_t OFF_BSUM = 400064;      // 256*4 -> 401,088
    const size_t OFF_FLAG = 401088;      // 64 -> 401,152
    const size_t OFF_EIDS = 401152;      // NE*4 -> 1,201,152
    const size_t OFF_WT   = 1201152;     // 1536*384*2 -> 2,380,800
    const size_t OFF_EBF  = 2380800;     // 50000*384*2 -> 40,780,800
    const size_t OFF_Q    = 40780800;    // 50000*384*2 -> 79,180,800

    if (ws_size < 79180800) return;      // diagnostic guard

    int*   indptr = (int*)(ws + OFF_IPTR);
    int*   cnt    = (int*)(ws + OFF_CNT);
    int*   bsum   = (int*)(ws + OFF_BSUM);
    int*   dtf    = (int*)(ws + OFF_FLAG);
    int*   eids   = (int*)(ws + OFF_EIDS);
    u16*   Wt     = (u16*)(ws + OFF_WT);
    u16*   ebf    = (u16*)(ws + OFF_EBF);     // bf16 embeddings, then preln
    u16*   qa     = (u16*)(ws + OFF_Q);       // q -> agg (in-place)
    u16*   preln  = ebf;                      // ebf dead after QKV GEMM
    u16*   kv     = (u16*)d_out;              // k|v, dead before final write

    const int NB_N = (NN + 255) / 256;   // 196
    const int NB_E = (NE + 255) / 256;   // 782

    detect_k<<<1, 256, 0, stream>>>((const u16*)emb, dtf);
    // fused zero | cast | packw : 196 + 9375 + 2304 = 11875 blocks
    prolog_k<<<196 + 9375 + 2304, 256, 0, stream>>>(emb, ebf, WQ, WK, WV, WO,
                                                    Wt, cnt, dtf);
    hist_k<<<NB_E, 256, 0, stream>>>(eidx, cnt);
    scan1_k<<<NB_N, 256, 0, stream>>>(cnt, indptr, bsum);
    scan2_k<<<1, 256, 0, stream>>>(bsum, NB_N);
    scan3_k<<<NB_N, 256, 0, stream>>>(indptr, bsum, cnt);
    scatter_k<<<NB_E, 256, 0, stream>>>(eidx, indptr, cnt, eids);

    // fused q|k|v projection, XCD-swizzled: 392 m-slots x 9 n-tiles
    gemm_k<0, 9><<<392 * 9, 256, 0, stream>>>(ebf, Wt, qa, kv, nullptr,
                                              nullptr, dtf, NN);

    attn_k<<<(NN + 3) / 4, 256, 0, stream>>>(qa, kv, eidx, eattr, WE,
                                             indptr, eids, dtf);

    // output projection + residual -> preln (ebf region, disjoint from qa)
    gemm_k<1, 3><<<392 * 3, 256, 0, stream>>>(qa, Wt + 1152 * 384, nullptr,
                                              nullptr, preln, emb, dtf, NN);

    ln_k<<<(NN + 3) / 4, 256, 0, stream>>>(preln, lng, lnb, d_out, dtf);
}

// Round 9
// 381.512 us; speedup vs baseline: 1.1484x; 1.0623x over previous
//
#include <hip/hip_runtime.h>

#define NN 50000
#define NE 200000
#define DD 384

typedef unsigned short u16;
typedef unsigned int   u32;
typedef __attribute__((ext_vector_type(8))) __bf16 bf16x8;
typedef __attribute__((ext_vector_type(8))) short  short8;
typedef __attribute__((ext_vector_type(4))) float  f32x4;

// ---------- bf16 helpers (raw ushort storage) ----------
__device__ __forceinline__ float bf2f(u16 v) {
    union { u32 u; float f; } x; x.u = ((u32)v) << 16; return x.f;
}
__device__ __forceinline__ u16 f2bf(float f) {
    union { float f; u32 u; } x; x.f = f;
    u32 r = x.u + 0x7fff + ((x.u >> 16) & 1);   // RNE
    return (u16)(r >> 16);
}

// async global->LDS, 16B per lane. LDS dest = wave-uniform base + lane*16
// (HW rule, m104/m108); our staging layout is exactly that.
__device__ __forceinline__ void gload16(const void* g, void* l) {
    __builtin_amdgcn_global_load_lds(
        (const __attribute__((address_space(1))) u32*)g,
        (__attribute__((address_space(3))) u32*)l, 16, 0, 0);
}

__device__ __forceinline__ float ldf(const void* p, size_t i, int dt) {
    return dt ? ((const float*)p)[i] : bf2f(((const u16*)p)[i]);
}

// ---------- detect dtype (block 0) + zero cnt (blocks 1..196) ----------
__global__ __launch_bounds__(256) void detect0_k(const u16* __restrict__ p,
                                                 int* __restrict__ flag,
                                                 int* __restrict__ cnt) {
    const int b = blockIdx.x;
    if (b == 0) {
        __shared__ int tot;
        if (threadIdx.x == 0) tot = 0;
        __syncthreads();
        int bad = 0;
        for (int i = threadIdx.x; i < 8192; i += 256) {
            u16 v = p[i];
            int e = (v >> 7) & 0xFF;
            if (e >= 0x86) bad++;
        }
        atomicAdd(&tot, bad);
        __syncthreads();
        if (threadIdx.x == 0) flag[0] = (tot > 400) ? 1 : 0;
        return;
    }
    int i = (b - 1) * 256 + threadIdx.x;
    if (i < NN) cnt[i] = 0;
}

// ---------- fused prologue: hist | cast(emb->bf16) | packw ----------
// All independent given: cnt zeroed and dtf written (detect0_k, previous
// kernel). hist first so its atomics overlap the cast's streaming.
// blocks [0,782): hist; [782,782+9375): cast; [10157,10157+2304): packw.
__global__ __launch_bounds__(256) void prolog_k(
    const void* __restrict__ emb, u16* __restrict__ ebf,
    const void* __restrict__ WQ, const void* __restrict__ WK,
    const void* __restrict__ WV, const void* __restrict__ WO,
    u16* __restrict__ Wt, int* __restrict__ cnt,
    const int* __restrict__ eidx, const int* __restrict__ dtf) {
    const int b = blockIdx.x;
    if (b < 782) {
        int e = b * 256 + threadIdx.x;
        if (e < NE) {
            int d = eidx[NE + e];
            if ((u32)d < NN) atomicAdd(&cnt[d], 1);
        }
        return;
    }
    if (b < 782 + 9375) {
        size_t i = ((size_t)(b - 782) * 256 + threadIdx.x) * 8;
        if (i >= (size_t)NN * 384) return;
        if (dtf[0]) {
            const float* s = (const float*)emb + i;
            f32x4 a0 = *(const f32x4*)s;
            f32x4 a1 = *(const f32x4*)(s + 4);
            short8 o;
            o[0] = (short)f2bf(a0[0]); o[1] = (short)f2bf(a0[1]);
            o[2] = (short)f2bf(a0[2]); o[3] = (short)f2bf(a0[3]);
            o[4] = (short)f2bf(a1[0]); o[5] = (short)f2bf(a1[1]);
            o[6] = (short)f2bf(a1[2]); o[7] = (short)f2bf(a1[3]);
            *(short8*)(ebf + i) = o;
        } else {
            *(short8*)(ebf + i) = *(const short8*)((const u16*)emb + i);
        }
        return;
    }
    int idx = (b - 782 - 9375) * 256 + threadIdx.x;
    if (idx >= 1536 * 384) return;
    int dt = dtf[0];
    int n = idx / 384, k = idx - n * 384;
    const void* W; int c;
    if (n < 384)       { W = WQ; c = n; }
    else if (n < 768)  { W = WK; c = n - 384; }
    else if (n < 1152) { W = WV; c = n - 768; }
    else               { W = WO; c = n - 1152; }
    size_t off = (size_t)k * 384 + c;
    Wt[idx] = dt ? f2bf(((const float*)W)[off]) : ((const u16*)W)[off];
}

// ---------- CSR scan + scatter ----------
__global__ __launch_bounds__(256) void scan1_k(const int* __restrict__ cnt,
                                               int* __restrict__ indptr,
                                               int* __restrict__ bsum) {
    __shared__ int tmp[256];
    int i = blockIdx.x * 256 + threadIdx.x;
    int v = (i < NN) ? cnt[i] : 0;
    tmp[threadIdx.x] = v;
    __syncthreads();
    #pragma unroll
    for (int off = 1; off < 256; off <<= 1) {
        int t = tmp[threadIdx.x];
        int a = (threadIdx.x >= off) ? tmp[threadIdx.x - off] : 0;
        __syncthreads();
        tmp[threadIdx.x] = t + a;
        __syncthreads();
    }
    if (i < NN) indptr[i + 1] = tmp[threadIdx.x];
    if (threadIdx.x == 255) bsum[blockIdx.x] = tmp[255];
}
__global__ __launch_bounds__(256) void scan2_k(int* __restrict__ bsum, int nb) {
    __shared__ int tmp[256];
    int v = (threadIdx.x < nb) ? bsum[threadIdx.x] : 0;
    tmp[threadIdx.x] = v;
    __syncthreads();
    #pragma unroll
    for (int off = 1; off < 256; off <<= 1) {
        int t = tmp[threadIdx.x];
        int a = (threadIdx.x >= off) ? tmp[threadIdx.x - off] : 0;
        __syncthreads();
        tmp[threadIdx.x] = t + a;
        __syncthreads();
    }
    if (threadIdx.x < nb) bsum[threadIdx.x] = tmp[threadIdx.x] - v;  // exclusive
}
__global__ void scan3_k(int* __restrict__ indptr, const int* __restrict__ bsum,
                        int* __restrict__ cnt) {
    int i = blockIdx.x * 256 + threadIdx.x;
    if (i < NN) { indptr[i + 1] += bsum[blockIdx.x]; cnt[i] = 0; }
    if (i == 0) indptr[0] = 0;
}
__global__ void scatter_k(const int* __restrict__ eidx, const int* __restrict__ indptr,
                          int* __restrict__ cur, int* __restrict__ eids) {
    int e = blockIdx.x * 256 + threadIdx.x;
    if (e < NE) {
        int d = eidx[NE + e];
        if ((u32)d < NN) {
            int p = atomicAdd(&cur[d], 1);
            int slot = indptr[d] + p;
            if ((u32)slot < NE) eids[slot] = e;
        }
    }
}

// ---------- MFMA GEMM, XCD-swizzled 1-D grid, BK=64 ----------
// 128x128 tile, 4 waves 2x2, 4x4 frags of 16x16x32 bf16. A always bf16.
// BK=64: 12 barrier-drain pairs per block; LDS 32 KB. Staging via
// global_load_lds width=16. Pure-store epilogue for BOTH modes (residual
// moved to ln_k — the 64 scattered epilogue loads were OUT's 3x per-block
// cost, R8 counters).
// MODE 0 (QKV): n<384 -> q (ld 384), n>=384 -> kv (ld 768).
// MODE 1 (OUT): C = bf16 preln = acc (no residual here).
template <int MODE, int NT>
__global__ __launch_bounds__(256) void gemm_k(
    const u16* __restrict__ A, const u16* __restrict__ Bt,
    u16* __restrict__ qd, u16* __restrict__ kvd, u16* __restrict__ preln,
    const int* __restrict__ dtf, int M) {
    __shared__ __align__(16) short As[2 * 128 * 32];   // slab ks: cols k0+ks*32..
    __shared__ __align__(16) short Bs[2 * 128 * 32];
    const int b    = blockIdx.x;
    const int xcd  = b & 7;
    const int j    = b >> 3;
    const int mg   = j / NT;
    const int nt   = j - mg * NT;
    const int m_idx = mg * 8 + xcd;
    if (m_idx >= (M + 127) / 128) return;
    const int m0 = m_idx * 128;
    const int n0 = nt * 128;
    const int tid  = threadIdx.x;
    const int lane = tid & 63;
    const int wave = tid >> 6;
    const int wm = (wave >> 1) * 64;
    const int wn = (wave & 1) * 64;
    const int q = lane >> 4;     // 0..3
    const int r = lane & 15;     // 0..15

    f32x4 acc[4][4];
    #pragma unroll
    for (int i = 0; i < 4; i++)
        #pragma unroll
        for (int jj = 0; jj < 4; jj++) acc[i][jj] = (f32x4)(0.0f);

    const int srow = tid >> 2;          // 0..63
    const int scol = (tid & 3) * 8;     // element offset in 32-wide K slab

    for (int kb = 0; kb < 6; ++kb) {
        const int k0 = kb * 64;
        #pragma unroll
        for (int h = 0; h < 4; ++h) {
            const int slab = h >> 1;
            const int row  = (h & 1) * 64 + srow;          // 0..127
            const int col  = k0 + slab * 32 + scol;
            int am = m0 + row; am = am < M ? am : M - 1;
            // dest byte = h*4096 + tid*16 -> slab (h>>1), row, col8 (tid&3)
            gload16(A  + (size_t)am * 384 + col,
                    (void*)(As + h * 2048 + wave * 512));
            gload16(Bt + (size_t)(n0 + row) * 384 + col,
                    (void*)(Bs + h * 2048 + wave * 512));
        }
        __syncthreads();            // compiler emits vmcnt(0) drain here
        #pragma unroll
        for (int ks = 0; ks < 2; ++ks) {
            bf16x8 af[4], bfr[4];
            #pragma unroll
            for (int i = 0; i < 4; i++)
                af[i] = *(const bf16x8*)&As[ks * 4096 + (wm + i * 16 + r) * 32 + q * 8];
            #pragma unroll
            for (int jj = 0; jj < 4; jj++)
                bfr[jj] = *(const bf16x8*)&Bs[ks * 4096 + (wn + jj * 16 + r) * 32 + q * 8];
            #pragma unroll
            for (int i = 0; i < 4; i++)
                #pragma unroll
                for (int jj = 0; jj < 4; jj++)
                    acc[i][jj] = __builtin_amdgcn_mfma_f32_16x16x32_bf16(
                        af[i], bfr[jj], acc[i][jj], 0, 0, 0);
        }
        __syncthreads();
    }

    // block-uniform destination routing
    u16* C; int ld, c0;
    if (MODE == 0) {
        if (n0 < 384) { C = qd;  ld = 384; c0 = n0; }
        else          { C = kvd; ld = 768; c0 = n0 - 384; }
    } else {
        C = preln; ld = 384; c0 = n0;
    }

    // D layout: col = lane&15, row = (lane>>4)*4 + reg   [measured m89/m91]
    #pragma unroll
    for (int i = 0; i < 4; i++) {
        #pragma unroll
        for (int rr = 0; rr < 4; ++rr) {
            int m = m0 + wm + i * 16 + q * 4 + rr;
            if (m >= M) continue;
            #pragma unroll
            for (int jj = 0; jj < 4; jj++) {
                int n = c0 + wn + jj * 16 + r;
                C[(size_t)m * ld + n] = f2bf(acc[i][jj][rr]);
            }
        }
    }
}

// ---------- per-node attention ----------
// wave per node; lanes 0-31 = head0, 32-63 = head1; 6 elems/lane (192/32).
__global__ __launch_bounds__(256) void attn_k(
    u16* __restrict__ qbuf,              // [NN][384] bf16, becomes agg
    const u16* __restrict__ kv,          // [NN][768] bf16 = k|v
    const int* __restrict__ eidx,
    const void* __restrict__ eattr, const void* __restrict__ WE,
    const int* __restrict__ indptr, const int* __restrict__ eids,
    const int* __restrict__ dtf) {
    int node = blockIdx.x * 4 + (threadIdx.x >> 6);
    if (node >= NN) return;
    int dt = dtf[0];
    int lane = threadIdx.x & 63;
    int half = lane >> 5;
    int j = lane & 31;
    int col = half * 192 + j * 6;

    float qv[6], we[6];
    {
        const u32* p = (const u32*)(qbuf + (size_t)node * 384 + col);
        #pragma unroll
        for (int t = 0; t < 3; t++) {
            u32 w = p[t];
            qv[2 * t] = bf2f(w & 0xffff); qv[2 * t + 1] = bf2f(w >> 16);
        }
        #pragma unroll
        for (int t = 0; t < 6; t++) we[t] = ldf(WE, col + t, dt);
    }
    int beg = indptr[node], end = indptr[node + 1];
    if (beg < 0) beg = 0; if (beg > NE) beg = NE;
    if (end < beg) end = beg; if (end > NE) end = NE;
    float m_run = -1e30f, l_run = 0.0f;
    float acc[6] = {0, 0, 0, 0, 0, 0};

    for (int it = beg; it < end; ++it) {
        int eid = eids[it];
        if ((u32)eid >= NE) eid = 0;
        int src = eidx[eid];                    // row 0 = src
        if ((u32)src >= NN) src = 0;
        float attr = ldf(eattr, eid, dt);
        const u32* kp = (const u32*)(kv + (size_t)src * 768 + col);
        const u32* vp = (const u32*)(kv + (size_t)src * 768 + 384 + col);
        float kj[6], vj[6];
        #pragma unroll
        for (int t = 0; t < 3; t++) {
            u32 wk = kp[t];
            kj[2 * t]     = bf2f(wk & 0xffff) + attr * we[2 * t];
            kj[2 * t + 1] = bf2f(wk >> 16)    + attr * we[2 * t + 1];
            u32 wv = vp[t];
            vj[2 * t]     = bf2f(wv & 0xffff) + attr * we[2 * t];
            vj[2 * t + 1] = bf2f(wv >> 16)    + attr * we[2 * t + 1];
        }
        float part = qv[0] * kj[0] + qv[1] * kj[1] + qv[2] * kj[2] +
                     qv[3] * kj[3] + qv[4] * kj[4] + qv[5] * kj[5];
        #pragma unroll
        for (int off = 1; off < 32; off <<= 1) part += __shfl_xor(part, off, 64);
        float s = part * 0.07216878364870323f;   // 1/sqrt(192)
        float mn = fmaxf(m_run, s);
        float corr = __expf(m_run - mn);
        float p = __expf(s - mn);
        l_run = l_run * corr + p;
        #pragma unroll
        for (int t = 0; t < 6; t++) acc[t] = acc[t] * corr + p * vj[t];
        m_run = mn;
    }
    float inv = (end > beg) ? 1.0f / (l_run + 1e-16f) : 0.0f;
    u16* ar = qbuf + (size_t)node * 384 + col;   // in-place over q row
    #pragma unroll
    for (int t = 0; t < 6; t++) ar[t] = f2bf(acc[t] * inv);
}

// ---------- LayerNorm + residual: wave per row ----------
// x = preln bf16 (WO*agg, no residual); resid = emb (fp32/bf16 per flag).
// v = x + resid (fp32 math), then LN. Residual access is lane-contiguous
// (24 B/lane) — coalesced, unlike the 64 scattered loads the GEMM epilogue
// used to do (R8: that was OUT GEMM's 3x per-block cost).
__global__ __launch_bounds__(256) void ln_k(const u16* __restrict__ x,
                                            const void* __restrict__ resid,
                                            const void* __restrict__ g,
                                            const void* __restrict__ b,
                                            void* __restrict__ out,
                                            const int* __restrict__ dtf) {
    int node = blockIdx.x * 4 + (threadIdx.x >> 6);
    if (node >= NN) return;
    int dt = dtf[0];
    int lane = threadIdx.x & 63;
    size_t o0 = (size_t)node * 384 + lane * 6;
    const u32* row = (const u32*)(x + o0);
    float v[6];
    #pragma unroll
    for (int t = 0; t < 3; t++) {
        u32 w = row[t];
        v[2 * t] = bf2f(w & 0xffff); v[2 * t + 1] = bf2f(w >> 16);
    }
    #pragma unroll
    for (int t = 0; t < 6; t++) v[t] += ldf(resid, o0 + t, dt);
    float s = v[0] + v[1] + v[2] + v[3] + v[4] + v[5];
    #pragma unroll
    for (int off = 1; off < 64; off <<= 1) s += __shfl_xor(s, off, 64);
    float mean = s * (1.0f / 384.0f);
    float sq = 0.0f;
    #pragma unroll
    for (int t = 0; t < 6; t++) { float d = v[t] - mean; sq += d * d; }
    #pragma unroll
    for (int off = 1; off < 64; off <<= 1) sq += __shfl_xor(sq, off, 64);
    float rstd = rsqrtf(sq * (1.0f / 384.0f) + 1e-5f);
    #pragma unroll
    for (int t = 0; t < 6; t++) {
        float gv = ldf(g, lane * 6 + t, dt), bv = ldf(b, lane * 6 + t, dt);
        float val = (v[t] - mean) * rstd * gv + bv;
        if (dt) ((float*)out)[o0 + t] = val;
        else    ((u16*)out)[o0 + t] = f2bf(val);
    }
}

// ---------- launch ----------
extern "C" void kernel_launch(void* const* d_in, const int* in_sizes, int n_in,
                              void* d_out, int out_size, void* d_ws, size_t ws_size,
                              hipStream_t stream) {
    const void* emb   = d_in[0];
    const int*  eidx  = (const int*)d_in[1];
    const void* eattr = d_in[2];
    const void* WQ    = d_in[3];
    const void* WK    = d_in[4];
    const void* WV    = d_in[5];
    const void* WE    = d_in[6];
    const void* WO    = d_in[7];
    const void* lng   = d_in[8];
    const void* lnb   = d_in[9];

    char* ws = (char*)d_ws;
    // ws layout — exactly 79,180,800 B:
    //   ints+flag+eids+Wt (2.38 MB) | ebf 38.4 MB | q/agg 38.4 MB
    // kv bf16 [NN][768] = 76.8 MB lives in d_out (dead until ln_k writes).
    // preln reuses the EBF region (dead after QKV GEMM) — never aliases A.
    const size_t OFF_IPTR = 0;           // (NN+1)*4 -> pad 200,064
    const size_t OFF_CNT  = 200064;      // NN*4 -> 400,064
    const size_t OFF_BSUM = 400064;      // 256*4 -> 401,088
    const size_t OFF_FLAG = 401088;      // 64 -> 401,152
    const size_t OFF_EIDS = 401152;      // NE*4 -> 1,201,152
    const size_t OFF_WT   = 1201152;     // 1536*384*2 -> 2,380,800
    const size_t OFF_EBF  = 2380800;     // 50000*384*2 -> 40,780,800
    const size_t OFF_Q    = 40780800;    // 50000*384*2 -> 79,180,800

    if (ws_size < 79180800) return;      // diagnostic guard

    int*   indptr = (int*)(ws + OFF_IPTR);
    int*   cnt    = (int*)(ws + OFF_CNT);
    int*   bsum   = (int*)(ws + OFF_BSUM);
    int*   dtf    = (int*)(ws + OFF_FLAG);
    int*   eids   = (int*)(ws + OFF_EIDS);
    u16*   Wt     = (u16*)(ws + OFF_WT);
    u16*   ebf    = (u16*)(ws + OFF_EBF);     // bf16 embeddings, then preln
    u16*   qa     = (u16*)(ws + OFF_Q);       // q -> agg (in-place)
    u16*   preln  = ebf;                      // ebf dead after QKV GEMM
    u16*   kv     = (u16*)d_out;              // k|v, dead before final write

    const int NB_N = (NN + 255) / 256;   // 196
    const int NB_E = (NE + 255) / 256;   // 782

    // 9-node chain: detect0 -> prolog(hist|cast|packw) -> scan1 -> scan2
    //               -> scan3 -> scatter -> gemmQKV -> attn -> gemmOUT -> ln
    detect0_k<<<197, 256, 0, stream>>>((const u16*)emb, dtf, cnt);
    prolog_k<<<782 + 9375 + 2304, 256, 0, stream>>>(emb, ebf, WQ, WK, WV, WO,
                                                    Wt, cnt, eidx, dtf);
    scan1_k<<<NB_N, 256, 0, stream>>>(cnt, indptr, bsum);
    scan2_k<<<1, 256, 0, stream>>>(bsum, NB_N);
    scan3_k<<<NB_N, 256, 0, stream>>>(indptr, bsum, cnt);
    scatter_k<<<NB_E, 256, 0, stream>>>(eidx, indptr, cnt, eids);

    // fused q|k|v projection, XCD-swizzled: 392 m-slots x 9 n-tiles
    gemm_k<0, 9><<<392 * 9, 256, 0, stream>>>(ebf, Wt, qa, kv, nullptr,
                                              dtf, NN);

    attn_k<<<(NN + 3) / 4, 256, 0, stream>>>(qa, kv, eidx, eattr, WE,
                                             indptr, eids, dtf);

    // output projection -> preln (pure store; residual moved to ln_k)
    gemm_k<1, 3><<<392 * 3, 256, 0, stream>>>(qa, Wt + 1152 * 384, nullptr,
                                              nullptr, preln, dtf, NN);

    ln_k<<<(NN + 3) / 4, 256, 0, stream>>>(preln, emb, lng, lnb, d_out, dtf);
}